// Round 5
// baseline (139.722 us; speedup 1.0000x reference)
//
#include <hip/hip_runtime.h>

#define K_SEL 103
typedef unsigned long long ull_t;
typedef _Float16 f16x8 __attribute__((ext_vector_type(8)));
typedef float f32x4 __attribute__((ext_vector_type(4)));

// ================= kall: single fused kernel with software grid barrier =====
// grid 512 x 512 thr; LDS 81680 B caps residency at exactly 2 blocks/CU and
// grid == 2 x 256 CUs -> ALL blocks co-resident (spin barrier cannot starve).
// Per block q:
//   L: xlh rows [32q,32q+32) = fp16(x @ W_lin^T + b); 132-entry W2th chunk
//      -> __syncthreads (drains stores to L2) -> agent-scope release arrive
//   S: selection + MLP -> Hs/ind/inv_s in LDS (no global round-trip)
//   spin (agent-scope acquire) until all 512 arrived  [xlh/W2th visible]
//   G: gather + 4x GEMM1 passes (8 bt) + M=8 GEMM2 vs W2th -> out
// Counter is reset each iteration by a 4-byte hipMemsetAsync in the graph.
__global__ __launch_bounds__(512, 4) void kall(const float* __restrict__ pos,
                                               const float* __restrict__ qpos,
                                               const float* __restrict__ Bmat,
                                               const float* __restrict__ W1,
                                               const float* __restrict__ b1,
                                               const float* __restrict__ x,
                                               const float* __restrict__ W,
                                               const float* __restrict__ b,
                                               _Float16* __restrict__ xlh,
                                               const float* __restrict__ W2,
                                               const float* __restrict__ filt,
                                               _Float16* __restrict__ W2th,
                                               const float* __restrict__ bias,
                                               unsigned* __restrict__ ctr,
                                               float* __restrict__ out) {
    __shared__ __align__(16) unsigned char smem[81680];
    // persist region (live across phases):
    _Float16* Hs    = (_Float16*)smem;               // 6144 halfs = 12288 B
    int*      ind   = (int*)(smem + 12288);          // 128 ints  = 512 B
    float*    inv_s = (float*)(smem + 12800);        // 16 B
    unsigned char* SG = smem + 12816;                // 68864 B scratch

    const int tid = threadIdx.x;
    const int q = blockIdx.x;
    const int lane = tid & 63;
    const int wid = tid >> 6;          // 0..7

    // ---------------- phase L: 32 xlh rows + W2th chunk --------------------
    {
        float* Wt = (float*)SG;                    // 64x65 floats = 16640 B
        if (tid < 132) {
            int t = q * 132 + tid;                 // 512*132 = 67584 exactly
            int d = t & 31;
            int e = t >> 5;
            int c = e & 63;
            int j = e >> 6;
            float v = (j < 32) ? W2[(c * 32 + d) * 32 + j] : filt[c * 32 + d];
            W2th[d * 2112 + e] = (_Float16)v;
        }
        for (int t = tid; t < 4096; t += 512)
            Wt[(t & 63) * 65 + (t >> 6)] = W[t];
        __syncthreads();
        const int i = tid & 63;
        const int sub = tid >> 6;                  // 0..7
        const float bi = b[i];
        const int r0 = q * 32 + sub * 4;
        float acc0 = bi, acc1 = bi, acc2 = bi, acc3 = bi;
        const float* xr = x + (size_t)r0 * 64;
        #pragma unroll 4
        for (int jj = 0; jj < 16; ++jj) {
            float4 v0 = *(const float4*)(xr + 0 * 64 + jj * 4);
            float4 v1 = *(const float4*)(xr + 1 * 64 + jj * 4);
            float4 v2 = *(const float4*)(xr + 2 * 64 + jj * 4);
            float4 v3 = *(const float4*)(xr + 3 * 64 + jj * 4);
            float w0 = Wt[(jj * 4 + 0) * 65 + i];
            float w1 = Wt[(jj * 4 + 1) * 65 + i];
            float w2 = Wt[(jj * 4 + 2) * 65 + i];
            float w3 = Wt[(jj * 4 + 3) * 65 + i];
            acc0 += v0.x * w0 + v0.y * w1 + v0.z * w2 + v0.w * w3;
            acc1 += v1.x * w0 + v1.y * w1 + v1.z * w2 + v1.w * w3;
            acc2 += v2.x * w0 + v2.y * w1 + v2.z * w2 + v2.w * w3;
            acc3 += v3.x * w0 + v3.y * w1 + v3.z * w2 + v3.w * w3;
        }
        xlh[(size_t)(r0 + 0) * 64 + i] = (_Float16)acc0;
        xlh[(size_t)(r0 + 1) * 64 + i] = (_Float16)acc1;
        xlh[(size_t)(r0 + 2) * 64 + i] = (_Float16)acc2;
        xlh[(size_t)(r0 + 3) * 64 + i] = (_Float16)acc3;
        __syncthreads();   // all block stores drained (vmcnt(0) before barrier)
        if (tid == 0)      // publish: L2 writeback + arrive (device scope)
            __hip_atomic_fetch_add(ctr, 1u, __ATOMIC_RELEASE,
                                   __HIP_MEMORY_SCOPE_AGENT);
    }

    // ---------------- phase S: select + MLP --------------------------------
    {
        unsigned* ebits   = (unsigned*)(SG);              // 8192 B
        unsigned* hist    = (unsigned*)(SG + 8192);       // 16384 B
        float*    W1s     = (float*)(SG + 24576);         // 4096 B
        float*    b1s     = (float*)(SG + 28672);
        float*    Bm      = (float*)(SG + 28800);
        int*      sel_v   = (int*)(SG + 28928);           // 104
        float*    sel_e   = (float*)(SG + 29344);         // 104
        ull_t*    bnd     = (ull_t*)(SG + 29760);         // 128
        int*      counters= (int*)(SG + 30784);           // 2
        int*      info    = (int*)(SG + 30792);           // 2
        float*    wred    = (float*)(SG + 30800);         // 8
        float*    emax_s  = (float*)(SG + 30832);         // 1
        unsigned* wscan   = (unsigned*)(SG + 30836);      // 8

        for (int t = tid; t < 1024; t += 512) W1s[t] = W1[t];
        if (tid < 32) { b1s[tid] = b1[tid]; Bm[tid] = Bmat[tid]; }
        if (tid < 2)  counters[tid] = 0;
        for (int t = tid; t < 1024; t += 512) ((uint4*)hist)[t] = make_uint4(0, 0, 0, 0);
        const float qp0 = qpos[q * 2 + 0];
        const float qp1 = qpos[q * 2 + 1];
        __syncthreads();

        float lmin = 1e30f;
        for (int v = tid; v < 2048; v += 512) {
            float2 p = ((const float2*)pos)[v];
            float d0 = qp0 - p.x;
            float d1 = qp1 - p.y;
            d0 += 0.5f; d0 -= floorf(d0); d0 -= 0.5f;
            d1 += 0.5f; d1 -= floorf(d1); d1 -= 0.5f;
            float e = d0 * d0 + d1 * d1;
            ebits[v] = __float_as_uint(e);
            lmin = fminf(lmin, e);
            int bb2 = (int)(e * 8192.0f); bb2 = (bb2 > 4095) ? 4095 : bb2;
            atomicAdd(&hist[bb2], 1u);
        }
        #pragma unroll
        for (int off = 32; off > 0; off >>= 1)
            lmin = fminf(lmin, __shfl_xor(lmin, off, 64));
        if (lane == 0) wred[wid] = lmin;
        __syncthreads();
        float e_min = wred[0];
        #pragma unroll
        for (int w2 = 1; w2 < 8; ++w2) e_min = fminf(e_min, wred[w2]);

        // ---- hist scan: 8 bins/thread
        unsigned lsum = 0;
        #pragma unroll
        for (int i = 0; i < 8; ++i) lsum += hist[tid * 8 + i];
        unsigned vq = lsum;
        #pragma unroll
        for (int off = 1; off < 64; off <<= 1) {
            unsigned n = __shfl_up(vq, off, 64);
            if (lane >= off) vq += n;
        }
        if (lane == 63) wscan[wid] = vq;
        __syncthreads();
        unsigned base = 0;
        for (int w2 = 0; w2 < wid; ++w2) base += wscan[w2];
        unsigned cum = base + vq - lsum;
        #pragma unroll
        for (int i = 0; i < 8; ++i) {
            unsigned cnt = hist[tid * 8 + i];
            if (cum <= 102u && 102u < cum + cnt) { info[0] = tid * 8 + i; info[1] = (int)cum; }
            cum += cnt;
        }
        __syncthreads();          // all hist reads done -> hist dead
        const int Bstar = info[0];
        const int L = info[1];
        const int need = K_SEL - L;

        {   // zero Hs (persist region)
            f16x8 z = {0, 0, 0, 0, 0, 0, 0, 0};
            for (int t = tid; t < 768; t += 512) ((f16x8*)Hs)[t] = z;
        }
        for (int v = tid; v < 2048; v += 512) {
            unsigned bb2 = ebits[v];
            float e = __uint_as_float(bb2);
            int bin = (int)(e * 8192.0f); bin = (bin > 4095) ? 4095 : bin;
            if (bin < Bstar) {
                int s2 = atomicAdd(&counters[0], 1);
                sel_v[s2] = v; sel_e[s2] = e;
            } else if (bin == Bstar) {
                int s2 = atomicAdd(&counters[1], 1);
                if (s2 < 128) bnd[s2] = (((ull_t)bb2) << 32) | (unsigned)v;
            }
        }
        __syncthreads();
        {   // parallel rank-select over boundary items (keys unique)
            int nb = counters[1]; if (nb > 128) nb = 128;
            if (tid < nb) {
                ull_t my = bnd[tid];
                int rank = 0;
                for (int i = 0; i < nb; ++i) rank += (bnd[i] < my);
                if (rank < need) {
                    sel_v[L + rank] = (int)(unsigned)(my & 0xffffffffull);
                    sel_e[L + rank] = __uint_as_float((unsigned)(my >> 32));
                }
                if (rank == need - 1)
                    emax_s[0] = __uint_as_float((unsigned)(my >> 32));
            }
        }
        __syncthreads();

        const float denom = (emax_s[0] - e_min) + 1e-8f;
        float w = 0.0f;
        if (tid < K_SEL) {
            w = __expf(-(sel_e[tid] - e_min) / denom);
            sel_e[tid] = w;
        }
        float sw = w;
        #pragma unroll
        for (int off = 32; off > 0; off >>= 1)
            sw += __shfl_xor(sw, off, 64);
        if (lane == 0) wred[wid] = sw;
        __syncthreads();
        if (tid == 0) {
            float tot = 0.0f;
            #pragma unroll
            for (int w2 = 0; w2 < 8; ++w2) tot += wred[w2];
            inv_s[0] = 1.0f / tot;
        }

        // ---- MLP with unnormalized w: 4 threads per k (8 outputs each)
        if (tid < 4 * K_SEL) {
            const int k = tid >> 2;
            const int io = (tid & 3) * 8;
            const int v = sel_v[k];
            const float wk = sel_e[k];
            float2 p = ((const float2*)pos)[v];
            float d0 = qp0 - p.x;
            float d1 = qp1 - p.y;
            d0 += 0.5f; d0 -= floorf(d0); d0 -= 0.5f;
            d1 += 0.5f; d1 -= floorf(d1); d1 -= 0.5f;
            float kf[32];
            #pragma unroll
            for (int f = 0; f < 16; ++f) {
                float t = d0 * Bm[f] + d1 * Bm[16 + f];   // revolutions
                float r = t - rintf(t);
                kf[f]      = __builtin_amdgcn_sinf(r);
                kf[16 + f] = __builtin_amdgcn_cosf(r);
            }
            #pragma unroll
            for (int i = io; i < io + 8; ++i) {
                float pre = b1s[i];
                #pragma unroll
                for (int jf = 0; jf < 32; ++jf) pre += kf[jf] * W1s[i * 32 + jf];
                float g = 0.5f * pre * (1.0f + erff(pre * 0.70710678118654752f));
                Hs[i * 128 + k] = (_Float16)(g * wk);
            }
            if (io == 0) {
                Hs[32 * 128 + k] = (_Float16)wk;
                ind[k] = v;
            }
        }
        __syncthreads();
        if (tid < 128 - K_SEL) ind[K_SEL + tid] = ind[tid];   // wrap entries
    }

    // ---------------- phase G: gather + GEMM1 (8 bt) + GEMM2 ---------------
    {
        const int h   = wid >> 2;          // bt-half within pass (0/1)
        const int cq  = wid & 3;           // channel quarter
        const int n0 = lane & 15;
        const int quad = lane >> 4;

        _Float16* Xg  = (_Float16*)SG;               // 2 x 8768 halfs = 35072 B
        _Float16* Zh8 = (_Float16*)(SG + 35072);     // 8 x 2112 halfs = 33792 B
        float* red    = (float*)SG;                  // aliases dead Xg

        // afr loads from LDS Hs (valid after the MLP barrier above)
        f16x8 afr[4][3];
        #pragma unroll
        for (int ks = 0; ks < 4; ++ks)
            #pragma unroll
            for (int r = 0; r < 3; ++r)
                afr[ks][r] = *(const f16x8*)(Hs + (r * 16 + n0) * 128 + ks * 32 + quad * 8);
        const float it = inv_s[0];

        // ---- software grid barrier: wait until all 512 blocks published L
        if (lane == 0) {
            while (__hip_atomic_load(ctr, __ATOMIC_ACQUIRE,
                                     __HIP_MEMORY_SCOPE_AGENT) < 512u)
                __builtin_amdgcn_s_sleep(8);
        }
        __syncthreads();          // spin done for all waves; ind wrap visible

        const int e0f = wid * 32 + quad * 8;
        f16x8 pf0 = *(const f16x8*)(W2th + (size_t)(0 * 16 + n0) * 2112 + e0f);
        f16x8 pf1 = *(const f16x8*)(W2th + (size_t)(1 * 16 + n0) * 2112 + e0f);

        int g_k[4], g_oct[4], g_h[4];
        #pragma unroll
        for (int i = 0; i < 4; ++i) {
            int t = tid + i * 512;
            g_h[i] = t >> 10;              // bt-half of this load
            g_k[i] = (t >> 3) & 127;
            g_oct[i] = t & 7;
        }

        {   // pass-0 gather: bt 0 (half 0) and bt 1 (half 1)
            f16x8 v0[4];
            #pragma unroll
            for (int i = 0; i < 4; ++i)
                v0[i] = *(const f16x8*)(xlh + ((size_t)g_h[i] * 2048 + ind[g_k[i]]) * 64 + g_oct[i] * 8);
            #pragma unroll
            for (int i = 0; i < 4; ++i) {
                int base = g_h[i] * 8768 + g_oct[i] * 1096 + g_k[i];
                #pragma unroll
                for (int jj = 0; jj < 8; ++jj) Xg[base + 136 * jj] = v0[i][jj];
            }
        }
        __syncthreads();

        const int cA = cq * 16 + n0;
        const int cswz = h * 8768 + cA * 136 + ((cA >> 3) << 3);

        #pragma unroll
        for (int p = 0; p < 4; ++p) {
            f16x8 vn[4];
            if (p < 3) {
                #pragma unroll
                for (int i = 0; i < 4; ++i)
                    vn[i] = *(const f16x8*)(xlh + ((size_t)(2 * (p + 1) + g_h[i]) * 2048 + ind[g_k[i]]) * 64 + g_oct[i] * 8);
            }
            f32x4 Dz[3];
            #pragma unroll
            for (int r = 0; r < 3; ++r) Dz[r] = (f32x4){0.f, 0.f, 0.f, 0.f};
            #pragma unroll
            for (int ks = 0; ks < 4; ++ks) {
                f16x8 bfr = *(const f16x8*)(&Xg[cswz + ks * 32 + quad * 8]);
                #pragma unroll
                for (int r = 0; r < 3; ++r)
                    Dz[r] = __builtin_amdgcn_mfma_f32_16x16x32_f16(afr[ks][r], bfr, Dz[r], 0, 0, 0);
            }
            __syncthreads();          // Xg reads done
            const int bt = 2 * p + h;
            #pragma unroll
            for (int r = 0; r < 3; ++r)
                #pragma unroll
                for (int reg = 0; reg < 4; ++reg) {
                    int j = r * 16 + quad * 4 + reg;
                    if (j < 33) Zh8[bt * 2112 + j * 64 + cA] = (_Float16)Dz[r][reg];
                }
            if (p < 3) {
                #pragma unroll
                for (int i = 0; i < 4; ++i) {
                    int base = g_h[i] * 8768 + g_oct[i] * 1096 + g_k[i];
                    #pragma unroll
                    for (int jj = 0; jj < 8; ++jj) Xg[base + 136 * jj] = vn[i][jj];
                }
                __syncthreads();
            }
        }
        __syncthreads();              // all Zh8 writes visible

        // ---- GEMM2: one M=8 pass, s == wid (mod 8), s in [0,66) ----------
        f32x4 D2[2][2];
        #pragma unroll
        for (int pp = 0; pp < 2; ++pp)
            #pragma unroll
            for (int dt = 0; dt < 2; ++dt) D2[pp][dt] = (f32x4){0.f, 0.f, 0.f, 0.f};
        {
            f16x8 a2 = {0, 0, 0, 0, 0, 0, 0, 0};
            if (n0 < 8) a2 = *(const f16x8*)(&Zh8[n0 * 2112 + e0f]);
            D2[0][0] = __builtin_amdgcn_mfma_f32_16x16x32_f16(a2, pf0, D2[0][0], 0, 0, 0);
            D2[0][1] = __builtin_amdgcn_mfma_f32_16x16x32_f16(a2, pf1, D2[0][1], 0, 0, 0);
        }
        int pp = 1;
        #pragma unroll 2
        for (int s = wid + 8; s < 66; s += 8) {
            const int e0 = s * 32 + quad * 8;
            f16x8 a2 = {0, 0, 0, 0, 0, 0, 0, 0};
            if (n0 < 8) a2 = *(const f16x8*)(&Zh8[n0 * 2112 + e0]);
            #pragma unroll
            for (int dt = 0; dt < 2; ++dt) {
                f16x8 bfr = *(const f16x8*)(W2th + (size_t)(dt * 16 + n0) * 2112 + e0);
                D2[pp][dt] = __builtin_amdgcn_mfma_f32_16x16x32_f16(a2, bfr, D2[pp][dt], 0, 0, 0);
            }
            pp ^= 1;
        }
        #pragma unroll
        for (int dt = 0; dt < 2; ++dt)
            D2[0][dt] = D2[0][dt] + D2[1][dt];

        // D rows: bt = quad*4 + reg -> quads 0,1 hold bt 0..7
        if (quad < 2) {
            #pragma unroll
            for (int dt = 0; dt < 2; ++dt)
                #pragma unroll
                for (int reg = 0; reg < 4; ++reg)
                    red[((wid * 2 + dt) * 8 + quad * 4 + reg) * 16 + n0] = D2[0][dt][reg];
        }
        __syncthreads();
        if (tid < 256) {
            const int bt = tid >> 5;
            const int d = tid & 31;
            const int dt = d >> 4;
            const int dn = d & 15;
            float s = 0.0f;
            #pragma unroll
            for (int w2 = 0; w2 < 8; ++w2)
                s += red[((w2 * 2 + dt) * 8 + bt) * 16 + dn];
            out[((size_t)bt * 512 + q) * 32 + d] = bias[d] + it * s;
        }
    }
}

// ---------------------------------------------------------------------------
extern "C" void kernel_launch(void* const* d_in, const int* in_sizes, int n_in,
                              void* d_out, int out_size, void* d_ws, size_t ws_size,
                              hipStream_t stream) {
    const float* x     = (const float*)d_in[0];   // (2,4,2048,64)
    const float* pos   = (const float*)d_in[1];   // (2048,2)
    const float* qpos  = (const float*)d_in[2];   // (512,2)
    const float* W_lin = (const float*)d_in[3];   // (64,64)
    const float* b_lin = (const float*)d_in[4];   // (64)
    const float* Bmat  = (const float*)d_in[5];   // (2,16)
    const float* W1    = (const float*)d_in[6];   // (32,32)
    const float* b1    = (const float*)d_in[7];   // (32)
    const float* W2    = (const float*)d_in[8];   // (2048,32)
    const float* filt  = (const float*)d_in[9];   // (2048)
    const float* bias  = (const float*)d_in[10];  // (32)
    float* out = (float*)d_out;

    float* ws = (float*)d_ws;
    _Float16* xlh  = (_Float16*)ws;               // 1048576 halfs = 2 MB
    _Float16* W2th = (_Float16*)(ws + 524288);    // 67584 halfs
    unsigned* ctr  = (unsigned*)(ws + 558080);    // 1 uint (grid barrier)

    hipMemsetAsync(ctr, 0, sizeof(unsigned), stream);   // graph-capturable
    kall<<<512, 512, 0, stream>>>(pos, qpos, Bmat, W1, b1, x, W_lin, b_lin,
                                  xlh, W2, filt, W2th, bias, ctr, out);
}

// Round 6
// 109.278 us; speedup vs baseline: 1.2786x; 1.2786x over previous
//
#include <hip/hip_runtime.h>

#define K_SEL 103
typedef unsigned long long ull_t;
typedef _Float16 f16x8 __attribute__((ext_vector_type(8)));
typedef float f32x4 __attribute__((ext_vector_type(4)));

// ================= K12: fused (k2 select+MLP | k1 lin+W2th), B=512 ==========
// grid 768 = exactly 3 blocks/CU x 256 CUs (one residency round):
// blocks [0,512) = per-query selection + MLP -> Hh; blocks [512,768) = lin.
// R6 conflict fixes (from R5 PMC: SQ_LDS_BANK_CONFLICT 5.39M):
//  - W1 transposed in LDS, stride 33 (was stride-32 same-bank 4-way reads)
//  - Hs writes: XOR col bit-5 by io-parity (was 8-way: row stride 64 words)
__global__ __launch_bounds__(512, 6) void k12(const float* __restrict__ pos,
                                              const float* __restrict__ qpos,
                                              const float* __restrict__ Bmat,
                                              const float* __restrict__ W1,
                                              const float* __restrict__ b1,
                                              _Float16* __restrict__ Hh,
                                              int* __restrict__ indg,
                                              float* __restrict__ invtot,
                                              const float* __restrict__ x,
                                              const float* __restrict__ W,
                                              const float* __restrict__ b,
                                              _Float16* __restrict__ xlh,
                                              const float* __restrict__ W2,
                                              const float* __restrict__ filt,
                                              _Float16* __restrict__ W2th) {
    __shared__ __align__(16) unsigned char smem[31008];
    const int tid = threadIdx.x;
    const int bid = blockIdx.x;
    const int lane = tid & 63;
    const int wid = tid >> 6;          // 0..7

    if (bid >= 512) {
        // ---------------- k1 path: 64 rows + W2th chunk --------------------
        const int bb = bid - 512;
        float* Wt = (float*)smem;                  // 64x65 (pad kills 64-way conflict)
        if (tid < 264) {
            int t = bb * 264 + tid;                // 256*264 = 67584 exactly
            int d = t & 31;
            int e = t >> 5;
            int c = e & 63;
            int j = e >> 6;
            float v = (j < 32) ? W2[(c * 32 + d) * 32 + j] : filt[c * 32 + d];
            W2th[d * 2112 + e] = (_Float16)v;
        }
        for (int t = tid; t < 4096; t += 512)
            Wt[(t & 63) * 65 + (t >> 6)] = W[t];
        __syncthreads();
        const int i = tid & 63;
        const int sub = tid >> 6;                  // 0..7
        const float bi = b[i];
        #pragma unroll
        for (int rr = 0; rr < 2; ++rr) {
            const int r0 = bb * 64 + rr * 32 + sub * 4;
            float acc0 = bi, acc1 = bi, acc2 = bi, acc3 = bi;
            const float* xr = x + (size_t)r0 * 64;
            #pragma unroll 4
            for (int jj = 0; jj < 16; ++jj) {
                float4 v0 = *(const float4*)(xr + 0 * 64 + jj * 4);
                float4 v1 = *(const float4*)(xr + 1 * 64 + jj * 4);
                float4 v2 = *(const float4*)(xr + 2 * 64 + jj * 4);
                float4 v3 = *(const float4*)(xr + 3 * 64 + jj * 4);
                float w0 = Wt[(jj * 4 + 0) * 65 + i];
                float w1 = Wt[(jj * 4 + 1) * 65 + i];
                float w2 = Wt[(jj * 4 + 2) * 65 + i];
                float w3 = Wt[(jj * 4 + 3) * 65 + i];
                acc0 += v0.x * w0 + v0.y * w1 + v0.z * w2 + v0.w * w3;
                acc1 += v1.x * w0 + v1.y * w1 + v1.z * w2 + v1.w * w3;
                acc2 += v2.x * w0 + v2.y * w1 + v2.z * w2 + v2.w * w3;
                acc3 += v3.x * w0 + v3.y * w1 + v3.z * w2 + v3.w * w3;
            }
            xlh[(size_t)(r0 + 0) * 64 + i] = (_Float16)acc0;
            xlh[(size_t)(r0 + 1) * 64 + i] = (_Float16)acc1;
            xlh[(size_t)(r0 + 2) * 64 + i] = (_Float16)acc2;
            xlh[(size_t)(r0 + 3) * 64 + i] = (_Float16)acc3;
        }
        return;
    }

    // ---------------- k2 path: select + MLP --------------------------------
    const int q = bid;
    unsigned* ebits   = (unsigned*)(smem);            // 8192 B
    unsigned* hist    = (unsigned*)(smem + 8192);     // 16384 B
    _Float16* Hs      = (_Float16*)(smem + 8192);     // 12288 B (alias hist)
    float*    W1t     = (float*)(smem + 24576);       // 33x32 f = 4224 B
    float*    b1s     = (float*)(smem + 28800);
    float*    Bm      = (float*)(smem + 28928);
    int*      sel_v   = (int*)(smem + 29056);         // 104
    float*    sel_e   = (float*)(smem + 29472);       // 104
    ull_t*    bnd     = (ull_t*)(smem + 29888);       // 128
    int*      counters= (int*)(smem + 30912);         // 2
    int*      info    = (int*)(smem + 30920);         // 2
    float*    wred    = (float*)(smem + 30928);       // 8
    float*    emax_s  = (float*)(smem + 30960);       // 1
    unsigned* wscan   = (unsigned*)(smem + 30964);    // 8

    for (int t = tid; t < 1024; t += 512)
        W1t[(t & 31) * 33 + (t >> 5)] = W1[t];        // transposed, stride 33
    if (tid < 32) { b1s[tid] = b1[tid]; Bm[tid] = Bmat[tid]; }
    if (tid < 2)  counters[tid] = 0;
    for (int t = tid; t < 1024; t += 512) ((uint4*)hist)[t] = make_uint4(0, 0, 0, 0);
    const float qp0 = qpos[q * 2 + 0];
    const float qp1 = qpos[q * 2 + 1];
    __syncthreads();

    float lmin = 1e30f;
    for (int v = tid; v < 2048; v += 512) {
        float2 p = ((const float2*)pos)[v];
        float d0 = qp0 - p.x;
        float d1 = qp1 - p.y;
        d0 += 0.5f; d0 -= floorf(d0); d0 -= 0.5f;
        d1 += 0.5f; d1 -= floorf(d1); d1 -= 0.5f;
        float e = d0 * d0 + d1 * d1;
        ebits[v] = __float_as_uint(e);
        lmin = fminf(lmin, e);
        int bb2 = (int)(e * 8192.0f); bb2 = (bb2 > 4095) ? 4095 : bb2;
        atomicAdd(&hist[bb2], 1u);
    }
    #pragma unroll
    for (int off = 32; off > 0; off >>= 1)
        lmin = fminf(lmin, __shfl_xor(lmin, off, 64));
    if (lane == 0) wred[wid] = lmin;
    __syncthreads();
    float e_min = wred[0];
    #pragma unroll
    for (int w2 = 1; w2 < 8; ++w2) e_min = fminf(e_min, wred[w2]);

    // ---- hist scan: 8 bins/thread
    unsigned lsum = 0;
    #pragma unroll
    for (int i = 0; i < 8; ++i) lsum += hist[tid * 8 + i];
    unsigned vq = lsum;
    #pragma unroll
    for (int off = 1; off < 64; off <<= 1) {
        unsigned n = __shfl_up(vq, off, 64);
        if (lane >= off) vq += n;
    }
    if (lane == 63) wscan[wid] = vq;
    __syncthreads();
    unsigned base = 0;
    for (int w2 = 0; w2 < wid; ++w2) base += wscan[w2];
    unsigned cum = base + vq - lsum;
    #pragma unroll
    for (int i = 0; i < 8; ++i) {
        unsigned cnt = hist[tid * 8 + i];
        if (cum <= 102u && 102u < cum + cnt) { info[0] = tid * 8 + i; info[1] = (int)cum; }
        cum += cnt;
    }
    __syncthreads();          // all hist reads done -> hist dead
    const int Bstar = info[0];
    const int L = info[1];
    const int need = K_SEL - L;

    {   // zero Hs (aliases dead hist)
        f16x8 z = {0, 0, 0, 0, 0, 0, 0, 0};
        for (int t = tid; t < 768; t += 512) ((f16x8*)Hs)[t] = z;
    }
    for (int v = tid; v < 2048; v += 512) {
        unsigned bb2 = ebits[v];
        float e = __uint_as_float(bb2);
        int bin = (int)(e * 8192.0f); bin = (bin > 4095) ? 4095 : bin;
        if (bin < Bstar) {
            int s2 = atomicAdd(&counters[0], 1);
            sel_v[s2] = v; sel_e[s2] = e;
        } else if (bin == Bstar) {
            int s2 = atomicAdd(&counters[1], 1);
            if (s2 < 128) bnd[s2] = (((ull_t)bb2) << 32) | (unsigned)v;
        }
    }
    __syncthreads();
    {   // parallel rank-select over boundary items (keys unique)
        int nb = counters[1]; if (nb > 128) nb = 128;
        if (tid < nb) {
            ull_t my = bnd[tid];
            int rank = 0;
            for (int i = 0; i < nb; ++i) rank += (bnd[i] < my);
            if (rank < need) {
                sel_v[L + rank] = (int)(unsigned)(my & 0xffffffffull);
                sel_e[L + rank] = __uint_as_float((unsigned)(my >> 32));
            }
            if (rank == need - 1)
                emax_s[0] = __uint_as_float((unsigned)(my >> 32));
        }
    }
    __syncthreads();

    const float denom = (emax_s[0] - e_min) + 1e-8f;
    float w = 0.0f;
    if (tid < K_SEL) {
        w = __expf(-(sel_e[tid] - e_min) / denom);
        sel_e[tid] = w;
    }
    float sw = w;
    #pragma unroll
    for (int off = 32; off > 0; off >>= 1)
        sw += __shfl_xor(sw, off, 64);
    if (lane == 0) wred[wid] = sw;
    __syncthreads();
    if (tid == 0) {
        float tot = 0.0f;
        #pragma unroll
        for (int w2 = 0; w2 < 8; ++w2) tot += wred[w2];
        invtot[q] = 1.0f / tot;
    }

    // ---- MLP with unnormalized w: 4 threads per k (8 outputs each)
    if (tid < 4 * K_SEL) {
        const int k = tid >> 2;
        const int io = (tid & 3) * 8;
        const int sw5 = ((tid & 3) & 1) << 5;      // Hs col-XOR (bank spread)
        const int v = sel_v[k];
        const float wk = sel_e[k];
        float2 p = ((const float2*)pos)[v];
        float d0 = qp0 - p.x;
        float d1 = qp1 - p.y;
        d0 += 0.5f; d0 -= floorf(d0); d0 -= 0.5f;
        d1 += 0.5f; d1 -= floorf(d1); d1 -= 0.5f;
        float kf[32];
        #pragma unroll
        for (int f = 0; f < 16; ++f) {
            float t = d0 * Bm[f] + d1 * Bm[16 + f];   // revolutions
            float r = t - rintf(t);
            kf[f]      = __builtin_amdgcn_sinf(r);
            kf[16 + f] = __builtin_amdgcn_cosf(r);
        }
        #pragma unroll
        for (int i = io; i < io + 8; ++i) {
            float pre = b1s[i];
            #pragma unroll
            for (int jf = 0; jf < 32; ++jf) pre += kf[jf] * W1t[jf * 33 + i];
            float g = 0.5f * pre * (1.0f + erff(pre * 0.70710678118654752f));
            Hs[i * 128 + (k ^ sw5)] = (_Float16)(g * wk);
        }
        if (io == 0) {
            Hs[32 * 128 + k] = (_Float16)wk;   // i=32: (i>>3)&1 = 0, no swizzle
            indg[q * K_SEL + k] = v;
        }
    }
    __syncthreads();
    {
        _Float16* hq = Hh + (size_t)q * 6144;
        for (int t = tid; t < 768; t += 512)
            ((f16x8*)hq)[t] = ((const f16x8*)Hs)[t];
    }
}

// ---------------- K3q: ONE block per q (512 thr, 8 waves), 8 bt ------------
// grid 512 = 2 blocks/CU (LDS 69504 B x2 <= 160K), 16 waves/CU.
// R6 conflict fixes: Zh8 col-XOR by (j>>2)&3 (write was 8-way) + bt-stride
// 2120 (a2 read was 8-lane same-bank); afr applies k12's Hs col swizzle.
__global__ __launch_bounds__(512, 4) void k3_main(const _Float16* __restrict__ xlh,
                                                  const _Float16* __restrict__ Hh,
                                                  const int* __restrict__ indg,
                                                  const _Float16* __restrict__ W2th,
                                                  const float* __restrict__ bias,
                                                  const float* __restrict__ invtot,
                                                  float* __restrict__ out) {
    const int q = blockIdx.x;
    const int tid = threadIdx.x;
    const int lane = tid & 63;
    const int wid = tid >> 6;          // 0..7
    const int h   = wid >> 2;          // bt-half within pass (0/1)
    const int cq  = wid & 3;           // channel quarter
    const int n0 = lane & 15;
    const int quad = lane >> 4;

    __shared__ __align__(16) unsigned char smem[69504];
    _Float16* Xg  = (_Float16*)smem;                 // 2 x 8768 halfs = 35072 B
    _Float16* Zh8 = (_Float16*)(smem + 35072);       // 8 x 2120 halfs = 33920 B
    int* ind_s    = (int*)(smem + 68992);            // 128 ints
    float* red    = (float*)smem;                    // aliases dead Xg (2048 f)

    const _Float16* hq = Hh + (size_t)q * 6144;
    f16x8 afr[4][3];
    #pragma unroll
    for (int ks = 0; ks < 4; ++ks)
        #pragma unroll
        for (int r = 0; r < 3; ++r)
            afr[ks][r] = *(const f16x8*)(hq + (r * 16 + n0) * 128 +
                                         ((ks * 32 + quad * 8) ^ ((n0 >> 3) << 5)));
    const float it = invtot[q];
    const int e0f = wid * 32 + quad * 8;             // flat e for W2th (global)
    f16x8 pf0 = *(const f16x8*)(W2th + (size_t)(0 * 16 + n0) * 2112 + e0f);
    f16x8 pf1 = *(const f16x8*)(W2th + (size_t)(1 * 16 + n0) * 2112 + e0f);
    if (tid < 128) {
        int kk = (tid < K_SEL) ? tid : tid - K_SEL;
        ind_s[tid] = indg[q * K_SEL + kk];
    }
    __syncthreads();

    int g_k[4], g_oct[4], g_h[4];
    #pragma unroll
    for (int i = 0; i < 4; ++i) {
        int t = tid + i * 512;
        g_h[i] = t >> 10;              // bt-half of this load
        g_k[i] = (t >> 3) & 127;
        g_oct[i] = t & 7;
    }

    {   // pass-0 gather: bt 0 (half 0) and bt 1 (half 1)
        f16x8 v0[4];
        #pragma unroll
        for (int i = 0; i < 4; ++i)
            v0[i] = *(const f16x8*)(xlh + ((size_t)g_h[i] * 2048 + ind_s[g_k[i]]) * 64 + g_oct[i] * 8);
        #pragma unroll
        for (int i = 0; i < 4; ++i) {
            int base = g_h[i] * 8768 + g_oct[i] * 1096 + g_k[i];
            #pragma unroll
            for (int jj = 0; jj < 8; ++jj) Xg[base + 136 * jj] = v0[i][jj];
        }
    }
    __syncthreads();

    const int cA = cq * 16 + n0;
    const int cswz = h * 8768 + cA * 136 + ((cA >> 3) << 3);

    #pragma unroll
    for (int p = 0; p < 4; ++p) {
        f16x8 vn[4];
        if (p < 3) {
            #pragma unroll
            for (int i = 0; i < 4; ++i)
                vn[i] = *(const f16x8*)(xlh + ((size_t)(2 * (p + 1) + g_h[i]) * 2048 + ind_s[g_k[i]]) * 64 + g_oct[i] * 8);
        }
        f32x4 Dz[3];
        #pragma unroll
        for (int r = 0; r < 3; ++r) Dz[r] = (f32x4){0.f, 0.f, 0.f, 0.f};
        #pragma unroll
        for (int ks = 0; ks < 4; ++ks) {
            f16x8 bfr = *(const f16x8*)(&Xg[cswz + ks * 32 + quad * 8]);
            #pragma unroll
            for (int r = 0; r < 3; ++r)
                Dz[r] = __builtin_amdgcn_mfma_f32_16x16x32_f16(afr[ks][r], bfr, Dz[r], 0, 0, 0);
        }
        __syncthreads();          // Xg reads done
        const int bt = 2 * p + h;
        #pragma unroll
        for (int r = 0; r < 3; ++r)
            #pragma unroll
            for (int reg = 0; reg < 4; ++reg) {
                int j = r * 16 + quad * 4 + reg;     // (j>>2)&3 == quad
                if (j < 33) Zh8[bt * 2120 + j * 64 + (cA ^ (quad << 4))] = (_Float16)Dz[r][reg];
            }
        if (p < 3) {
            #pragma unroll
            for (int i = 0; i < 4; ++i) {
                int base = g_h[i] * 8768 + g_oct[i] * 1096 + g_k[i];
                #pragma unroll
                for (int jj = 0; jj < 8; ++jj) Xg[base + 136 * jj] = vn[i][jj];
            }
            __syncthreads();
        }
    }
    __syncthreads();              // all Zh8 writes visible

    // ---- GEMM2: one M=8 pass, s == wid (mod 8), s in [0,66) ---------------
    // Zh8 phys col = logical ^ (((j>>2)&3)<<4), j = s>>1 (matches write side)
    f32x4 D2[2][2];
    #pragma unroll
    for (int pp = 0; pp < 2; ++pp)
        #pragma unroll
        for (int dt = 0; dt < 2; ++dt) D2[pp][dt] = (f32x4){0.f, 0.f, 0.f, 0.f};
    {
        const int s = wid;
        const int ja = s >> 1;
        const int phys = (((s & 1) << 5) + quad * 8) ^ (((s >> 3) & 3) << 4);
        f16x8 a2 = {0, 0, 0, 0, 0, 0, 0, 0};
        if (n0 < 8) a2 = *(const f16x8*)(&Zh8[n0 * 2120 + ja * 64 + phys]);
        D2[0][0] = __builtin_amdgcn_mfma_f32_16x16x32_f16(a2, pf0, D2[0][0], 0, 0, 0);
        D2[0][1] = __builtin_amdgcn_mfma_f32_16x16x32_f16(a2, pf1, D2[0][1], 0, 0, 0);
    }
    int pp = 1;
    #pragma unroll 2
    for (int s = wid + 8; s < 66; s += 8) {
        const int e0 = s * 32 + quad * 8;            // flat e for W2th (global)
        const int ja = s >> 1;
        const int phys = (((s & 1) << 5) + quad * 8) ^ (((s >> 3) & 3) << 4);
        f16x8 a2 = {0, 0, 0, 0, 0, 0, 0, 0};
        if (n0 < 8) a2 = *(const f16x8*)(&Zh8[n0 * 2120 + ja * 64 + phys]);
        #pragma unroll
        for (int dt = 0; dt < 2; ++dt) {
            f16x8 bfr = *(const f16x8*)(W2th + (size_t)(dt * 16 + n0) * 2112 + e0);
            D2[pp][dt] = __builtin_amdgcn_mfma_f32_16x16x32_f16(a2, bfr, D2[pp][dt], 0, 0, 0);
        }
        pp ^= 1;
    }
    #pragma unroll
    for (int dt = 0; dt < 2; ++dt)
        D2[0][dt] = D2[0][dt] + D2[1][dt];

    // D rows: bt = quad*4 + reg -> quads 0,1 hold bt 0..7
    if (quad < 2) {
        #pragma unroll
        for (int dt = 0; dt < 2; ++dt)
            #pragma unroll
            for (int reg = 0; reg < 4; ++reg)
                red[((wid * 2 + dt) * 8 + quad * 4 + reg) * 16 + n0] = D2[0][dt][reg];
    }
    __syncthreads();
    if (tid < 256) {
        const int bt = tid >> 5;
        const int d = tid & 31;
        const int dt = d >> 4;
        const int dn = d & 15;
        float s = 0.0f;
        #pragma unroll
        for (int w2 = 0; w2 < 8; ++w2)
            s += red[((w2 * 2 + dt) * 8 + bt) * 16 + dn];
        out[((size_t)bt * 512 + q) * 32 + d] = bias[d] + it * s;
    }
}

// ---------------------------------------------------------------------------
extern "C" void kernel_launch(void* const* d_in, const int* in_sizes, int n_in,
                              void* d_out, int out_size, void* d_ws, size_t ws_size,
                              hipStream_t stream) {
    const float* x     = (const float*)d_in[0];   // (2,4,2048,64)
    const float* pos   = (const float*)d_in[1];   // (2048,2)
    const float* qpos  = (const float*)d_in[2];   // (512,2)
    const float* W_lin = (const float*)d_in[3];   // (64,64)
    const float* b_lin = (const float*)d_in[4];   // (64)
    const float* Bmat  = (const float*)d_in[5];   // (2,16)
    const float* W1    = (const float*)d_in[6];   // (32,32)
    const float* b1    = (const float*)d_in[7];   // (32)
    const float* W2    = (const float*)d_in[8];   // (2048,32)
    const float* filt  = (const float*)d_in[9];   // (2048)
    const float* bias  = (const float*)d_in[10];  // (32)
    float* out = (float*)d_out;

    float* ws = (float*)d_ws;
    _Float16* xlh    = (_Float16*)ws;               // 1048576 halfs
    _Float16* Hh     = (_Float16*)(ws + 524288);    // 512*6144 halfs
    int*      indg   = (int*)(ws + 2097152);        // 52736 ints
    _Float16* W2th   = (_Float16*)(ws + 2150144);   // 32*2112 halfs
    float*    invtot = ws + 2183936;                // 512 floats

    k12<<<768, 512, 0, stream>>>(pos, qpos, Bmat, W1, b1, Hh, indg, invtot,
                                 x, W_lin, b_lin, xlh, W2, filt, W2th);
    k3_main<<<512, 512, 0, stream>>>(xlh, Hh, indg, W2th, bias, invtot, out);
}